// Round 1
// baseline (9218.631 us; speedup 1.0000x reference)
//
#include <hip/hip_runtime.h>
#include <stdint.h>

// LPDNet forward on gfx950.
// Layout decisions:
//   h     : (B,N,64) fp32 rows  -> coalesced gather + fp32-exact knn distances
//   featb : (B,N,512) bf16 rows -> [x1 | x2 | x3], rows feed conv3 GEMM and x2 gather
//   idx1/idx2 : (B,N,20) int32
// bf16 everywhere in the conv path (fp32 accum); tolerance is 2% of max|ref|.

#define NB 8
#define NP 4096
#define NPTS (NB*NP)

typedef float  floatx4 __attribute__((ext_vector_type(4)));
typedef short  short8  __attribute__((ext_vector_type(8)));

__device__ __forceinline__ unsigned short f2bf(float f) {
  union { float f; uint32_t u; } v; v.f = f;
  uint32_t r = v.u + 0x7fffu + ((v.u >> 16) & 1u);   // RNE
  return (unsigned short)(r >> 16);
}
__device__ __forceinline__ float bf2f(unsigned short h) {
  union { uint32_t u; float f; } v; v.u = ((uint32_t)h) << 16;
  return v.f;
}

__device__ __forceinline__ floatx4 mfma_bf16(short8 a, short8 b, floatx4 c) {
  return __builtin_amdgcn_mfma_f32_16x16x32_bf16(a, b, c, 0, 0, 0);
}

// ---------------- K0: fp32 -> bf16 weight conversion (runs every launch) ----
__global__ void cvt_weights(const float* a, int na, unsigned short* ab,
                            const float* b, int nb, unsigned short* bb,
                            const float* c, int nc, unsigned short* cb,
                            const float* d, int nd, unsigned short* db) {
  int i = blockIdx.x * 256 + threadIdx.x;
  if (i < na) ab[i] = f2bf(a[i]);
  if (i < nb) bb[i] = f2bf(b[i]);
  if (i < nc) cb[i] = f2bf(c[i]);
  if (i < nd) db[i] = f2bf(d[i]);
}

// ---------------- K1: conv1(3->64)+relu, conv2(64->64)+relu, plus xx sums ---
// One wave per point. h fp32 (B,N,64); hh = sum h^2; cc = sum coord^2.
__global__ __launch_bounds__(256) void conv12(
    const float* __restrict__ xin, const float* __restrict__ w1,
    const float* __restrict__ b1, const float* __restrict__ w2,
    const float* __restrict__ b2, float* __restrict__ h,
    float* __restrict__ hh, float* __restrict__ cc) {
  int wave = threadIdx.x >> 6, lane = threadIdx.x & 63;
  int p = blockIdx.x * 4 + wave;                    // grid 8192
  __shared__ float s_h1[4][64];
  const float* xp = xin + p * 3;
  float c0 = xp[0], c1 = xp[1], c2 = xp[2];
  float v = b1[lane] + w1[lane*3+0]*c0 + w1[lane*3+1]*c1 + w1[lane*3+2]*c2;
  s_h1[wave][lane] = fmaxf(v, 0.f);
  __syncthreads();
  float acc = b2[lane];
  const float* wr = w2 + lane * 64;
  #pragma unroll
  for (int c = 0; c < 64; c += 4) {
    floatx4 w4 = *(const floatx4*)(wr + c);
    acc += w4[0]*s_h1[wave][c]   + w4[1]*s_h1[wave][c+1]
         + w4[2]*s_h1[wave][c+2] + w4[3]*s_h1[wave][c+3];
  }
  acc = fmaxf(acc, 0.f);
  h[p*64 + lane] = acc;
  float sq = acc * acc;
  #pragma unroll
  for (int off = 32; off; off >>= 1) sq += __shfl_xor(sq, off, 64);
  if (lane == 0) { hh[p] = sq; cc[p] = c0*c0 + c1*c1 + c2*c2; }
}

// ---------------- K2: fused pairwise distance + top-20 -----------------------
// 64 rows/block. m-tiles of 64 staged transposed in LDS; 256 threads compute a
// 64x64 dot tile (4x4 register tiles); 64 threads maintain per-row top-20 lists.
// score = 2*dot - xx[r] - xx[m] (exact fp32, includes self) matches reference;
// ties broken by lower index like jax.lax.top_k. Static LDS = 62,208 B (<64K).
template<int C>
__global__ __launch_bounds__(256) void knn_topk(
    const float* __restrict__ X, const float* __restrict__ XX,
    int* __restrict__ idx_out) {
  __shared__ float rowsT[C][68];   // pad 68: 16B-aligned float4 rows
  __shared__ float mT[C][68];
  __shared__ float dots[64][65];   // pad 65: conflict-free per-row scan
  __shared__ float xxR[64];
  __shared__ float xxM[64];
  __shared__ float lv[64][20];
  __shared__ int   li[64][20];
  int b = blockIdx.y;
  int r0 = blockIdx.x * 64;
  int t = threadIdx.x;
  const float* Xb = X + (size_t)b * NP * C;
  for (int e = t; e < C * 64; e += 256) {
    int r = e / C, c = e - r * C;
    rowsT[c][r] = Xb[(r0 + r) * C + c];
  }
  if (t < 64) {
    xxR[t] = XX[b * NP + r0 + t];
    for (int s = 0; s < 20; s++) { lv[t][s] = -__builtin_inff(); li[t][s] = 0x7fffffff; }
  }
  float minval = -__builtin_inff(); int minidx = 0x7fffffff, minpos = 0;
  int tm = t & 15, tr = t >> 4;
  for (int mt = 0; mt < NP / 64; mt++) {
    __syncthreads();                       // prior scan done before restage
    int m0 = mt * 64;
    for (int e = t; e < C * 64; e += 256) {
      int r = e / C, c = e - r * C;
      mT[c][r] = Xb[(m0 + r) * C + c];
    }
    if (t < 64) xxM[t] = XX[b * NP + m0 + t];
    __syncthreads();
    float acc[4][4];
    #pragma unroll
    for (int i = 0; i < 4; i++)
      #pragma unroll
      for (int j = 0; j < 4; j++) acc[i][j] = 0.f;
    for (int c = 0; c < C; c++) {
      floatx4 av = *(floatx4*)&rowsT[c][tr * 4];
      floatx4 bv = *(floatx4*)&mT[c][tm * 4];
      #pragma unroll
      for (int i = 0; i < 4; i++)
        #pragma unroll
        for (int j = 0; j < 4; j++) acc[i][j] += av[i] * bv[j];
    }
    #pragma unroll
    for (int i = 0; i < 4; i++)
      #pragma unroll
      for (int j = 0; j < 4; j++)
        dots[tr*4 + i][tm*4 + j] = 2.f * acc[i][j] - xxR[tr*4 + i] - xxM[tm*4 + j];
    __syncthreads();
    if (t < 64) {                          // one list owner per row
      for (int m = 0; m < 64; m++) {
        float v = dots[t][m];
        int gi = m0 + m;
        if (v > minval || (v == minval && gi < minidx)) {
          lv[t][minpos] = v; li[t][minpos] = gi;
          float wv = __builtin_inff(); int wi = -1, wp = 0;
          for (int s = 0; s < 20; s++) {
            float sv = lv[t][s]; int si = li[t][s];
            if (sv < wv || (sv == wv && si > wi)) { wv = sv; wi = si; wp = s; }
          }
          minval = wv; minidx = wi; minpos = wp;
        }
      }
    }
  }
  __syncthreads();
  if (t < 64) {
    int base = (b * NP + r0 + t) * 20;
    for (int sel = 0; sel < 20; sel++) {
      float bv = -__builtin_inff(); int bi = 0x7fffffff, bs = 0;
      for (int s = 0; s < 20; s++) {
        float v = lv[t][s]; int gi = li[t][s];
        if (v > bv || (v == bv && gi < bi)) { bv = v; bi = gi; bs = s; }
      }
      idx_out[base + sel] = bi;
      lv[t][bs] = -__builtin_inff(); li[t][bs] = 0x7fffffff;
    }
  }
}

// ---------------- K3: graph_feature(h,idx1) -> dg1 -> max -> dg2 -> max ------
// One block per point. A = g0 (20x128 padded to 32) bf16 in LDS; B = weight rows
// streamed from global (32KB, L1-resident). MFMA 16x16x32, fp32 accum.
// D mapping: row(=A m-index k-slot) = quad*4+reg, col(=B n-index o) = lane&15.
__global__ __launch_bounds__(256) void dg_stage(
    const float* __restrict__ h, const int* __restrict__ idx1,
    const unsigned short* __restrict__ w1b, const float* __restrict__ bia1,
    const unsigned short* __restrict__ w2b, const float* __restrict__ bia2,
    unsigned short* __restrict__ featb) {
  __shared__ unsigned short s_a[32][136];   // pad 136: 16B-aligned, 2-way banks
  __shared__ unsigned short s_v[32][136];
  __shared__ int s_nb[20];
  int p = blockIdx.x;
  int b = p >> 12, n = p & 4095;
  int t = threadIdx.x;
  int lane = t & 63, wave = t >> 6;
  if (t < 20) s_nb[t] = idx1[p * 20 + t];
  __syncthreads();
  const float* hb = h + (size_t)b * NP * 64;
  const float* hc = hb + n * 64;
  for (int e = t; e < 2560; e += 256) {     // build g0 = [nbr-ctr | ctr]
    int k = e >> 7, c = e & 127;
    float v = (c < 64) ? (hb[s_nb[k] * 64 + c] - hc[c]) : hc[c - 64];
    s_a[k][c] = f2bf(v);
  }
  for (int e = t; e < 1536; e += 256) s_a[20 + (e >> 7)][e & 127] = 0;
  __syncthreads();
  int quad = lane >> 4, mrow = lane & 15;
  int nblock = wave * 32;
  floatx4 acc[2][2];
  #pragma unroll
  for (int i = 0; i < 2; i++)
    #pragma unroll
    for (int j = 0; j < 2; j++) acc[i][j] = (floatx4)0.f;
  #pragma unroll
  for (int ks = 0; ks < 4; ks++) {
    int k0 = ks * 32 + quad * 8;
    short8 a0 = *(short8*)&s_a[mrow][k0];
    short8 a1 = *(short8*)&s_a[16 + mrow][k0];
    short8 w0 = *(const short8*)(w1b + (nblock + mrow) * 128 + k0);
    short8 w1v = *(const short8*)(w1b + (nblock + 16 + mrow) * 128 + k0);
    acc[0][0] = mfma_bf16(a0, w0, acc[0][0]);
    acc[1][0] = mfma_bf16(a1, w0, acc[1][0]);
    acc[0][1] = mfma_bf16(a0, w1v, acc[0][1]);
    acc[1][1] = mfma_bf16(a1, w1v, acc[1][1]);
  }
  #pragma unroll
  for (int mt = 0; mt < 2; mt++)
    #pragma unroll
    for (int ns = 0; ns < 2; ns++)
      #pragma unroll
      for (int r = 0; r < 4; r++) {
        int m = mt * 16 + quad * 4 + r;
        int o = nblock + ns * 16 + mrow;
        s_v[m][o] = f2bf(fmaxf(acc[mt][ns][r] + bia1[o], 0.f));
      }
  __syncthreads();
  if (t < 128) {                            // x1 = max_k v1 (bf16 max == max then round)
    float mx = 0.f;
    for (int k = 0; k < 20; k++) mx = fmaxf(mx, bf2f(s_v[k][t]));
    featb[p * 512 + t] = f2bf(mx);
  }
  #pragma unroll
  for (int i = 0; i < 2; i++)
    #pragma unroll
    for (int j = 0; j < 2; j++) acc[i][j] = (floatx4)0.f;
  #pragma unroll
  for (int ks = 0; ks < 4; ks++) {
    int k0 = ks * 32 + quad * 8;
    short8 a0 = *(short8*)&s_v[mrow][k0];
    short8 a1 = *(short8*)&s_v[16 + mrow][k0];
    short8 w0 = *(const short8*)(w2b + (nblock + mrow) * 128 + k0);
    short8 w1v = *(const short8*)(w2b + (nblock + 16 + mrow) * 128 + k0);
    acc[0][0] = mfma_bf16(a0, w0, acc[0][0]);
    acc[1][0] = mfma_bf16(a1, w0, acc[1][0]);
    acc[0][1] = mfma_bf16(a0, w1v, acc[0][1]);
    acc[1][1] = mfma_bf16(a1, w1v, acc[1][1]);
  }
  float vmax[2] = {0.f, 0.f};
  #pragma unroll
  for (int mt = 0; mt < 2; mt++)
    #pragma unroll
    for (int ns = 0; ns < 2; ns++)
      #pragma unroll
      for (int r = 0; r < 4; r++) {
        int m = mt * 16 + quad * 4 + r;
        if (m < 20) {
          int o = nblock + ns * 16 + mrow;
          vmax[ns] = fmaxf(vmax[ns], fmaxf(acc[mt][ns][r] + bia2[o], 0.f));
        }
      }
  #pragma unroll
  for (int ns = 0; ns < 2; ns++) {
    float v = vmax[ns];
    v = fmaxf(v, __shfl_xor(v, 16, 64));
    v = fmaxf(v, __shfl_xor(v, 32, 64));
    if (lane < 16) featb[p * 512 + 128 + nblock + ns * 16 + lane] = f2bf(v);
  }
}

// ---------------- K4: graph_feature(x2,idx2) -> sn1 -> max -------------------
__global__ __launch_bounds__(256) void sn_stage(
    const int* __restrict__ idx2, const unsigned short* __restrict__ wb,
    const float* __restrict__ bias, unsigned short* __restrict__ featb) {
  __shared__ unsigned short s_a[32][264];
  __shared__ int s_nb[20];
  int p = blockIdx.x;
  int b = p >> 12;
  int t = threadIdx.x;
  int lane = t & 63, wave = t >> 6;
  if (t < 20) s_nb[t] = idx2[p * 20 + t];
  __syncthreads();
  const unsigned short* x2b = featb + (size_t)b * NP * 512 + 128;
  const unsigned short* x2c = featb + (size_t)p * 512 + 128;
  for (int e = t; e < 5120; e += 256) {
    int k = e >> 8, c = e & 255;
    float v = (c < 128) ? (bf2f(x2b[(size_t)s_nb[k] * 512 + c]) - bf2f(x2c[c]))
                        : bf2f(x2c[c - 128]);
    s_a[k][c] = f2bf(v);
  }
  for (int e = t; e < 3072; e += 256) s_a[20 + (e >> 8)][e & 255] = 0;
  __syncthreads();
  int quad = lane >> 4, mrow = lane & 15;
  int nblock = wave * 64;
  floatx4 acc[2][4];
  #pragma unroll
  for (int i = 0; i < 2; i++)
    #pragma unroll
    for (int j = 0; j < 4; j++) acc[i][j] = (floatx4)0.f;
  #pragma unroll
  for (int ks = 0; ks < 8; ks++) {
    int k0 = ks * 32 + quad * 8;
    short8 a0 = *(short8*)&s_a[mrow][k0];
    short8 a1 = *(short8*)&s_a[16 + mrow][k0];
    #pragma unroll
    for (int ns = 0; ns < 4; ns++) {
      short8 w = *(const short8*)(wb + (nblock + ns * 16 + mrow) * 256 + k0);
      acc[0][ns] = mfma_bf16(a0, w, acc[0][ns]);
      acc[1][ns] = mfma_bf16(a1, w, acc[1][ns]);
    }
  }
  float vmax[4] = {0.f, 0.f, 0.f, 0.f};
  #pragma unroll
  for (int mt = 0; mt < 2; mt++)
    #pragma unroll
    for (int ns = 0; ns < 4; ns++)
      #pragma unroll
      for (int r = 0; r < 4; r++) {
        int m = mt * 16 + quad * 4 + r;
        if (m < 20) {
          int o = nblock + ns * 16 + mrow;
          vmax[ns] = fmaxf(vmax[ns], fmaxf(acc[mt][ns][r] + bias[o], 0.f));
        }
      }
  #pragma unroll
  for (int ns = 0; ns < 4; ns++) {
    float v = vmax[ns];
    v = fmaxf(v, __shfl_xor(v, 16, 64));
    v = fmaxf(v, __shfl_xor(v, 32, 64));
    if (lane < 16) featb[p * 512 + 256 + nblock + ns * 16 + lane] = f2bf(v);
  }
}

// ---------------- K5: conv3 GEMM: out[o][p] = relu(w3[o,:]·feat[p,:] + b3) ---
// M-dim = o (1024) so stores over p (=n) coalesce. 128x128 tile, K-chunks of 32.
__global__ __launch_bounds__(256) void conv3_gemm(
    const unsigned short* __restrict__ w3b, const unsigned short* __restrict__ featb,
    const float* __restrict__ b3, float* __restrict__ out) {
  __shared__ unsigned short s_a[128][40];   // w3 rows (o), pad 40: aligned, 2-way banks
  __shared__ unsigned short s_b[128][40];   // feat rows (p)
  int o0 = blockIdx.x * 128, p0 = blockIdx.y * 128;
  int t = threadIdx.x, lane = t & 63, wave = t >> 6;
  int wy = wave >> 1, wx = wave & 1;
  int quad = lane >> 4, l15 = lane & 15;
  floatx4 acc[4][4];
  #pragma unroll
  for (int i = 0; i < 4; i++)
    #pragma unroll
    for (int j = 0; j < 4; j++) acc[i][j] = (floatx4)0.f;
  for (int kc = 0; kc < 16; kc++) {
    __syncthreads();
    for (int e = t; e < 512; e += 256) {
      int r = e >> 2, c8 = (e & 3) * 8;
      *(short8*)&s_a[r][c8] = *(const short8*)(w3b + (size_t)(o0 + r) * 512 + kc * 32 + c8);
    }
    for (int e = t; e < 512; e += 256) {
      int r = e >> 2, c8 = (e & 3) * 8;
      *(short8*)&s_b[r][c8] = *(const short8*)(featb + (size_t)(p0 + r) * 512 + kc * 32 + c8);
    }
    __syncthreads();
    int k0 = quad * 8;
    short8 af[4], bfr[4];
    #pragma unroll
    for (int i = 0; i < 4; i++) af[i] = *(short8*)&s_a[wy * 64 + i * 16 + l15][k0];
    #pragma unroll
    for (int j = 0; j < 4; j++) bfr[j] = *(short8*)&s_b[wx * 64 + j * 16 + l15][k0];
    #pragma unroll
    for (int i = 0; i < 4; i++)
      #pragma unroll
      for (int j = 0; j < 4; j++) acc[i][j] = mfma_bf16(af[i], bfr[j], acc[i][j]);
  }
  #pragma unroll
  for (int i = 0; i < 4; i++)
    #pragma unroll
    for (int j = 0; j < 4; j++) {
      int pl = p0 + wx * 64 + j * 16 + l15;
      int bI = pl >> 12, n = pl & 4095;
      #pragma unroll
      for (int r = 0; r < 4; r++) {
        int o = o0 + wy * 64 + i * 16 + quad * 4 + r;
        out[(size_t)(bI * 1024 + o) * 4096 + n] = fmaxf(acc[i][j][r] + b3[o], 0.f);
      }
    }
}

// ---------------- launcher ---------------------------------------------------
extern "C" void kernel_launch(void* const* d_in, const int* in_sizes, int n_in,
                              void* d_out, int out_size, void* d_ws, size_t ws_size,
                              hipStream_t stream) {
  const float* x    = (const float*)d_in[0];
  const float* w1   = (const float*)d_in[1];
  const float* b1   = (const float*)d_in[2];
  const float* w2   = (const float*)d_in[3];
  const float* b2   = (const float*)d_in[4];
  const float* wdg1 = (const float*)d_in[5];
  const float* bdg1 = (const float*)d_in[6];
  const float* wdg2 = (const float*)d_in[7];
  const float* bdg2 = (const float*)d_in[8];
  const float* wsn1 = (const float*)d_in[9];
  const float* bsn1 = (const float*)d_in[10];
  const float* w3   = (const float*)d_in[11];
  const float* b3   = (const float*)d_in[12];

  float* ws = (float*)d_ws;                 // offsets in floats (all 16B-aligned)
  float* h  = ws;                           // 2,097,152
  float* hh = ws + 2097152;                 //    32,768
  float* cc = ws + 2129920;                 //    32,768
  int* idx1 = (int*)(ws + 2162688);         //   655,360
  int* idx2 = (int*)(ws + 2818048);         //   655,360
  unsigned short* featb = (unsigned short*)(ws + 3473408);   // 16,777,216 bf16
  unsigned short* wdg1b = (unsigned short*)(ws + 11862016);  // 16,384 bf16
  unsigned short* wdg2b = (unsigned short*)(ws + 11870208);
  unsigned short* wsn1b = (unsigned short*)(ws + 11878400);  // 65,536 bf16
  unsigned short* w3b   = (unsigned short*)(ws + 11911168);  // 524,288 bf16

  cvt_weights<<<2048, 256, 0, stream>>>(wdg1, 16384, wdg1b, wdg2, 16384, wdg2b,
                                        wsn1, 65536, wsn1b, w3, 524288, w3b);
  conv12<<<8192, 256, 0, stream>>>(x, w1, b1, w2, b2, h, hh, cc);
  knn_topk<64><<<dim3(64, 8), 256, 0, stream>>>(h, hh, idx1);
  knn_topk<3><<<dim3(64, 8), 256, 0, stream>>>(x, cc, idx2);
  dg_stage<<<32768, 256, 0, stream>>>(h, idx1, wdg1b, bdg1, wdg2b, bdg2, featb);
  sn_stage<<<32768, 256, 0, stream>>>(idx2, wsn1b, bsn1, featb);
  conv3_gemm<<<dim3(8, 256), 256, 0, stream>>>(w3b, featb, b3, (float*)d_out);
}

// Round 2
// 3694.071 us; speedup vs baseline: 2.4955x; 2.4955x over previous
//
#include <hip/hip_runtime.h>
#include <stdint.h>

// LPDNet forward on gfx950.
// Layout decisions:
//   h     : (B,N,64) fp32 rows  -> coalesced gather + fp32-exact knn distances
//   featb : (B,N,512) bf16 rows -> [x1 | x2 | x3], rows feed conv3 GEMM and x2 gather
//   idx1/idx2 : (B,N,20) int32
// bf16 everywhere in the conv path (fp32 accum); tolerance is 2% of max|ref|.

#define NB 8
#define NP 4096
#define NPTS (NB*NP)

typedef float  floatx4 __attribute__((ext_vector_type(4)));
typedef short  short8  __attribute__((ext_vector_type(8)));

__device__ __forceinline__ unsigned short f2bf(float f) {
  union { float f; uint32_t u; } v; v.f = f;
  uint32_t r = v.u + 0x7fffu + ((v.u >> 16) & 1u);   // RNE
  return (unsigned short)(r >> 16);
}
__device__ __forceinline__ float bf2f(unsigned short h) {
  union { uint32_t u; float f; } v; v.u = ((uint32_t)h) << 16;
  return v.f;
}

__device__ __forceinline__ floatx4 mfma_bf16(short8 a, short8 b, floatx4 c) {
  return __builtin_amdgcn_mfma_f32_16x16x32_bf16(a, b, c, 0, 0, 0);
}

// ---------------- K0: fp32 -> bf16 weight conversion (runs every launch) ----
__global__ void cvt_weights(const float* a, int na, unsigned short* ab,
                            const float* b, int nb, unsigned short* bb,
                            const float* c, int nc, unsigned short* cb,
                            const float* d, int nd, unsigned short* db) {
  int i = blockIdx.x * 256 + threadIdx.x;
  if (i < na) ab[i] = f2bf(a[i]);
  if (i < nb) bb[i] = f2bf(b[i]);
  if (i < nc) cb[i] = f2bf(c[i]);
  if (i < nd) db[i] = f2bf(d[i]);
}

// ---------------- K1: conv1(3->64)+relu, conv2(64->64)+relu, plus xx sums ---
__global__ __launch_bounds__(256) void conv12(
    const float* __restrict__ xin, const float* __restrict__ w1,
    const float* __restrict__ b1, const float* __restrict__ w2,
    const float* __restrict__ b2, float* __restrict__ h,
    float* __restrict__ hh, float* __restrict__ cc) {
  int wave = threadIdx.x >> 6, lane = threadIdx.x & 63;
  int p = blockIdx.x * 4 + wave;                    // grid 8192
  __shared__ float s_h1[4][64];
  const float* xp = xin + p * 3;
  float c0 = xp[0], c1 = xp[1], c2 = xp[2];
  float v = b1[lane] + w1[lane*3+0]*c0 + w1[lane*3+1]*c1 + w1[lane*3+2]*c2;
  s_h1[wave][lane] = fmaxf(v, 0.f);
  __syncthreads();
  float acc = b2[lane];
  const float* wr = w2 + lane * 64;
  #pragma unroll
  for (int c = 0; c < 64; c += 4) {
    floatx4 w4 = *(const floatx4*)(wr + c);
    acc += w4[0]*s_h1[wave][c]   + w4[1]*s_h1[wave][c+1]
         + w4[2]*s_h1[wave][c+2] + w4[3]*s_h1[wave][c+3];
  }
  acc = fmaxf(acc, 0.f);
  h[p*64 + lane] = acc;
  float sq = acc * acc;
  #pragma unroll
  for (int off = 32; off; off >>= 1) sq += __shfl_xor(sq, off, 64);
  if (lane == 0) { hh[p] = sq; cc[p] = c0*c0 + c1*c1 + c2*c2; }
}

// ---------------- K2: fused pairwise distance + parallel top-20 --------------
// 64 rows/block, m-tiles of 64. Compute: 256 threads = 4x16 grid of 4x4 fp32
// register tiles. Selection: 4 threads per row (row = t>>2, sub = t&3), each
// scans 16 columns/tile into a REGISTER top-20 (unrolled cndmask insert; no
// dynamic indexing, no LDS lists). Final: 20 rounds of shfl_xor(1,2) argmax
// over the 4 lanes with (value, lower-index) tie-break == jax.lax.top_k order.
template<int C>
__global__ __launch_bounds__(256) void knn_topk(
    const float* __restrict__ X, const float* __restrict__ XX,
    int* __restrict__ idx_out) {
  __shared__ float rowsT[C][68];
  __shared__ float mT[C][68];
  __shared__ float dots[64][68];   // pad 68: float4-aligned rows
  __shared__ float xxR[64];
  __shared__ float xxM[64];
  int b = blockIdx.y;
  int r0 = blockIdx.x * 64;
  int t = threadIdx.x;
  const float* Xb = X + (size_t)b * NP * C;
  for (int e = t; e < C * 64; e += 256) {
    int r = e / C, c = e - r * C;
    rowsT[c][r] = Xb[(r0 + r) * C + c];
  }
  if (t < 64) xxR[t] = XX[b * NP + r0 + t];

  float lv[20]; int li[20];
  #pragma unroll
  for (int s = 0; s < 20; s++) { lv[s] = -__builtin_inff(); li[s] = 0x7fffffff; }
  float minval = -__builtin_inff(); int minpos = 0;

  int tm = t & 15, tr = t >> 4;         // compute mapping
  int row = t >> 2, sub = t & 3;        // selection mapping

  for (int mt = 0; mt < NP / 64; mt++) {
    int m0 = mt * 64;
    for (int e = t; e < C * 64; e += 256) {
      int r = e / C, c = e - r * C;
      mT[c][r] = Xb[(m0 + r) * C + c];
    }
    if (t < 64) xxM[t] = XX[b * NP + m0 + t];
    __syncthreads();                       // staging done; prior select done
    float acc[4][4];
    #pragma unroll
    for (int i = 0; i < 4; i++)
      #pragma unroll
      for (int j = 0; j < 4; j++) acc[i][j] = 0.f;
    for (int c = 0; c < C; c++) {
      floatx4 av = *(floatx4*)&rowsT[c][tr * 4];
      floatx4 bv = *(floatx4*)&mT[c][tm * 4];
      #pragma unroll
      for (int i = 0; i < 4; i++)
        #pragma unroll
        for (int j = 0; j < 4; j++) acc[i][j] += av[i] * bv[j];
    }
    #pragma unroll
    for (int i = 0; i < 4; i++) {
      floatx4 sv;
      #pragma unroll
      for (int j = 0; j < 4; j++)
        sv[j] = 2.f * acc[i][j] - xxR[tr*4 + i] - xxM[tm*4 + j];
      *(floatx4*)&dots[tr*4 + i][tm*4] = sv;
    }
    __syncthreads();                       // dots ready
    // selection: 16 columns for (row, sub)
    #pragma unroll
    for (int i = 0; i < 16; i++) {
      float v = dots[row][sub * 16 + i];
      if (v > minval) {                    // later equal values never displace
        int gi = m0 + sub * 16 + i;
        #pragma unroll
        for (int s = 0; s < 20; s++)
          if (s == minpos) { lv[s] = v; li[s] = gi; }
        // recompute worst (lowest value; among ties, highest index gets evicted next)
        minval = __builtin_inff(); int minidx = -1;
        #pragma unroll
        for (int s = 0; s < 20; s++) {
          bool worse = lv[s] < minval || (lv[s] == minval && li[s] > minidx);
          if (worse) { minval = lv[s]; minidx = li[s]; minpos = s; }
        }
      }
    }
  }
  // merge 4 per-thread lists -> row top-20, ordered like jax.lax.top_k
  int base = (b * NP + r0 + row) * 20;
  for (int sel = 0; sel < 20; sel++) {
    float mybv = -__builtin_inff(); int mybi = 0x7fffffff, mybs = 0;
    #pragma unroll
    for (int s = 0; s < 20; s++) {
      bool better = lv[s] > mybv || (lv[s] == mybv && li[s] < mybi);
      if (better) { mybv = lv[s]; mybi = li[s]; mybs = s; }
    }
    float bv = mybv; int bi = mybi;
    float ov = __shfl_xor(bv, 1, 64); int oi = __shfl_xor(bi, 1, 64);
    if (ov > bv || (ov == bv && oi < bi)) { bv = ov; bi = oi; }
    ov = __shfl_xor(bv, 2, 64); oi = __shfl_xor(bi, 2, 64);
    if (ov > bv || (ov == bv && oi < bi)) { bv = ov; bi = oi; }
    if (sub == 0) idx_out[base + sel] = bi;
    if (bi == mybi) {                      // column sets disjoint -> unique owner
      #pragma unroll
      for (int s = 0; s < 20; s++)
        if (s == mybs) { lv[s] = -__builtin_inff(); li[s] = 0x7fffffff; }
    }
  }
}

// ---------------- K3: graph_feature(h,idx1) -> dg1 -> max -> dg2 -> max ------
__global__ __launch_bounds__(256) void dg_stage(
    const float* __restrict__ h, const int* __restrict__ idx1,
    const unsigned short* __restrict__ w1b, const float* __restrict__ bia1,
    const unsigned short* __restrict__ w2b, const float* __restrict__ bia2,
    unsigned short* __restrict__ featb) {
  __shared__ unsigned short s_a[32][136];
  __shared__ unsigned short s_v[32][136];
  __shared__ int s_nb[20];
  int p = blockIdx.x;
  int b = p >> 12, n = p & 4095;
  int t = threadIdx.x;
  int lane = t & 63, wave = t >> 6;
  if (t < 20) s_nb[t] = idx1[p * 20 + t];
  __syncthreads();
  const float* hb = h + (size_t)b * NP * 64;
  const float* hc = hb + n * 64;
  for (int e = t; e < 2560; e += 256) {
    int k = e >> 7, c = e & 127;
    float v = (c < 64) ? (hb[s_nb[k] * 64 + c] - hc[c]) : hc[c - 64];
    s_a[k][c] = f2bf(v);
  }
  for (int e = t; e < 1536; e += 256) s_a[20 + (e >> 7)][e & 127] = 0;
  __syncthreads();
  int quad = lane >> 4, mrow = lane & 15;
  int nblock = wave * 32;
  floatx4 acc[2][2];
  #pragma unroll
  for (int i = 0; i < 2; i++)
    #pragma unroll
    for (int j = 0; j < 2; j++) acc[i][j] = (floatx4)0.f;
  #pragma unroll
  for (int ks = 0; ks < 4; ks++) {
    int k0 = ks * 32 + quad * 8;
    short8 a0 = *(short8*)&s_a[mrow][k0];
    short8 a1 = *(short8*)&s_a[16 + mrow][k0];
    short8 w0 = *(const short8*)(w1b + (nblock + mrow) * 128 + k0);
    short8 w1v = *(const short8*)(w1b + (nblock + 16 + mrow) * 128 + k0);
    acc[0][0] = mfma_bf16(a0, w0, acc[0][0]);
    acc[1][0] = mfma_bf16(a1, w0, acc[1][0]);
    acc[0][1] = mfma_bf16(a0, w1v, acc[0][1]);
    acc[1][1] = mfma_bf16(a1, w1v, acc[1][1]);
  }
  #pragma unroll
  for (int mt = 0; mt < 2; mt++)
    #pragma unroll
    for (int ns = 0; ns < 2; ns++)
      #pragma unroll
      for (int r = 0; r < 4; r++) {
        int m = mt * 16 + quad * 4 + r;
        int o = nblock + ns * 16 + mrow;
        s_v[m][o] = f2bf(fmaxf(acc[mt][ns][r] + bia1[o], 0.f));
      }
  __syncthreads();
  if (t < 128) {
    float mx = 0.f;
    for (int k = 0; k < 20; k++) mx = fmaxf(mx, bf2f(s_v[k][t]));
    featb[p * 512 + t] = f2bf(mx);
  }
  #pragma unroll
  for (int i = 0; i < 2; i++)
    #pragma unroll
    for (int j = 0; j < 2; j++) acc[i][j] = (floatx4)0.f;
  #pragma unroll
  for (int ks = 0; ks < 4; ks++) {
    int k0 = ks * 32 + quad * 8;
    short8 a0 = *(short8*)&s_v[mrow][k0];
    short8 a1 = *(short8*)&s_v[16 + mrow][k0];
    short8 w0 = *(const short8*)(w2b + (nblock + mrow) * 128 + k0);
    short8 w1v = *(const short8*)(w2b + (nblock + 16 + mrow) * 128 + k0);
    acc[0][0] = mfma_bf16(a0, w0, acc[0][0]);
    acc[1][0] = mfma_bf16(a1, w0, acc[1][0]);
    acc[0][1] = mfma_bf16(a0, w1v, acc[0][1]);
    acc[1][1] = mfma_bf16(a1, w1v, acc[1][1]);
  }
  float vmax[2] = {0.f, 0.f};
  #pragma unroll
  for (int mt = 0; mt < 2; mt++)
    #pragma unroll
    for (int ns = 0; ns < 2; ns++)
      #pragma unroll
      for (int r = 0; r < 4; r++) {
        int m = mt * 16 + quad * 4 + r;
        if (m < 20) {
          int o = nblock + ns * 16 + mrow;
          vmax[ns] = fmaxf(vmax[ns], fmaxf(acc[mt][ns][r] + bia2[o], 0.f));
        }
      }
  #pragma unroll
  for (int ns = 0; ns < 2; ns++) {
    float v = vmax[ns];
    v = fmaxf(v, __shfl_xor(v, 16, 64));
    v = fmaxf(v, __shfl_xor(v, 32, 64));
    if (lane < 16) featb[p * 512 + 128 + nblock + ns * 16 + lane] = f2bf(v);
  }
}

// ---------------- K4: graph_feature(x2,idx2) -> sn1 -> max -------------------
__global__ __launch_bounds__(256) void sn_stage(
    const int* __restrict__ idx2, const unsigned short* __restrict__ wb,
    const float* __restrict__ bias, unsigned short* __restrict__ featb) {
  __shared__ unsigned short s_a[32][264];
  __shared__ int s_nb[20];
  int p = blockIdx.x;
  int b = p >> 12;
  int t = threadIdx.x;
  int lane = t & 63, wave = t >> 6;
  if (t < 20) s_nb[t] = idx2[p * 20 + t];
  __syncthreads();
  const unsigned short* x2b = featb + (size_t)b * NP * 512 + 128;
  const unsigned short* x2c = featb + (size_t)p * 512 + 128;
  for (int e = t; e < 5120; e += 256) {
    int k = e >> 8, c = e & 255;
    float v = (c < 128) ? (bf2f(x2b[(size_t)s_nb[k] * 512 + c]) - bf2f(x2c[c]))
                        : bf2f(x2c[c - 128]);
    s_a[k][c] = f2bf(v);
  }
  for (int e = t; e < 3072; e += 256) s_a[20 + (e >> 8)][e & 255] = 0;
  __syncthreads();
  int quad = lane >> 4, mrow = lane & 15;
  int nblock = wave * 64;
  floatx4 acc[2][4];
  #pragma unroll
  for (int i = 0; i < 2; i++)
    #pragma unroll
    for (int j = 0; j < 4; j++) acc[i][j] = (floatx4)0.f;
  #pragma unroll
  for (int ks = 0; ks < 8; ks++) {
    int k0 = ks * 32 + quad * 8;
    short8 a0 = *(short8*)&s_a[mrow][k0];
    short8 a1 = *(short8*)&s_a[16 + mrow][k0];
    #pragma unroll
    for (int ns = 0; ns < 4; ns++) {
      short8 w = *(const short8*)(wb + (nblock + ns * 16 + mrow) * 256 + k0);
      acc[0][ns] = mfma_bf16(a0, w, acc[0][ns]);
      acc[1][ns] = mfma_bf16(a1, w, acc[1][ns]);
    }
  }
  float vmax[4] = {0.f, 0.f, 0.f, 0.f};
  #pragma unroll
  for (int mt = 0; mt < 2; mt++)
    #pragma unroll
    for (int ns = 0; ns < 4; ns++)
      #pragma unroll
      for (int r = 0; r < 4; r++) {
        int m = mt * 16 + quad * 4 + r;
        if (m < 20) {
          int o = nblock + ns * 16 + mrow;
          vmax[ns] = fmaxf(vmax[ns], fmaxf(acc[mt][ns][r] + bias[o], 0.f));
        }
      }
  #pragma unroll
  for (int ns = 0; ns < 4; ns++) {
    float v = vmax[ns];
    v = fmaxf(v, __shfl_xor(v, 16, 64));
    v = fmaxf(v, __shfl_xor(v, 32, 64));
    if (lane < 16) featb[p * 512 + 256 + nblock + ns * 16 + lane] = f2bf(v);
  }
}

// ---------------- K5: conv3 GEMM ---------------------------------------------
__global__ __launch_bounds__(256) void conv3_gemm(
    const unsigned short* __restrict__ w3b, const unsigned short* __restrict__ featb,
    const float* __restrict__ b3, float* __restrict__ out) {
  __shared__ unsigned short s_a[128][40];
  __shared__ unsigned short s_b[128][40];
  int o0 = blockIdx.x * 128, p0 = blockIdx.y * 128;
  int t = threadIdx.x, lane = t & 63, wave = t >> 6;
  int wy = wave >> 1, wx = wave & 1;
  int quad = lane >> 4, l15 = lane & 15;
  floatx4 acc[4][4];
  #pragma unroll
  for (int i = 0; i < 4; i++)
    #pragma unroll
    for (int j = 0; j < 4; j++) acc[i][j] = (floatx4)0.f;
  for (int kc = 0; kc < 16; kc++) {
    __syncthreads();
    for (int e = t; e < 512; e += 256) {
      int r = e >> 2, c8 = (e & 3) * 8;
      *(short8*)&s_a[r][c8] = *(const short8*)(w3b + (size_t)(o0 + r) * 512 + kc * 32 + c8);
    }
    for (int e = t; e < 512; e += 256) {
      int r = e >> 2, c8 = (e & 3) * 8;
      *(short8*)&s_b[r][c8] = *(const short8*)(featb + (size_t)(p0 + r) * 512 + kc * 32 + c8);
    }
    __syncthreads();
    int k0 = quad * 8;
    short8 af[4], bfr[4];
    #pragma unroll
    for (int i = 0; i < 4; i++) af[i] = *(short8*)&s_a[wy * 64 + i * 16 + l15][k0];
    #pragma unroll
    for (int j = 0; j < 4; j++) bfr[j] = *(short8*)&s_b[wx * 64 + j * 16 + l15][k0];
    #pragma unroll
    for (int i = 0; i < 4; i++)
      #pragma unroll
      for (int j = 0; j < 4; j++) acc[i][j] = mfma_bf16(af[i], bfr[j], acc[i][j]);
  }
  #pragma unroll
  for (int i = 0; i < 4; i++)
    #pragma unroll
    for (int j = 0; j < 4; j++) {
      int pl = p0 + wx * 64 + j * 16 + l15;
      int bI = pl >> 12, n = pl & 4095;
      #pragma unroll
      for (int r = 0; r < 4; r++) {
        int o = o0 + wy * 64 + i * 16 + quad * 4 + r;
        out[(size_t)(bI * 1024 + o) * 4096 + n] = fmaxf(acc[i][j][r] + b3[o], 0.f);
      }
    }
}

// ---------------- launcher ---------------------------------------------------
extern "C" void kernel_launch(void* const* d_in, const int* in_sizes, int n_in,
                              void* d_out, int out_size, void* d_ws, size_t ws_size,
                              hipStream_t stream) {
  const float* x    = (const float*)d_in[0];
  const float* w1   = (const float*)d_in[1];
  const float* b1   = (const float*)d_in[2];
  const float* w2   = (const float*)d_in[3];
  const float* b2   = (const float*)d_in[4];
  const float* wdg1 = (const float*)d_in[5];
  const float* bdg1 = (const float*)d_in[6];
  const float* wdg2 = (const float*)d_in[7];
  const float* bdg2 = (const float*)d_in[8];
  const float* wsn1 = (const float*)d_in[9];
  const float* bsn1 = (const float*)d_in[10];
  const float* w3   = (const float*)d_in[11];
  const float* b3   = (const float*)d_in[12];

  float* ws = (float*)d_ws;
  float* h  = ws;                           // 2,097,152
  float* hh = ws + 2097152;                 //    32,768
  float* cc = ws + 2129920;                 //    32,768
  int* idx1 = (int*)(ws + 2162688);         //   655,360
  int* idx2 = (int*)(ws + 2818048);         //   655,360
  unsigned short* featb = (unsigned short*)(ws + 3473408);   // 16,777,216 bf16
  unsigned short* wdg1b = (unsigned short*)(ws + 11862016);
  unsigned short* wdg2b = (unsigned short*)(ws + 11870208);
  unsigned short* wsn1b = (unsigned short*)(ws + 11878400);
  unsigned short* w3b   = (unsigned short*)(ws + 11911168);

  cvt_weights<<<2048, 256, 0, stream>>>(wdg1, 16384, wdg1b, wdg2, 16384, wdg2b,
                                        wsn1, 65536, wsn1b, w3, 524288, w3b);
  conv12<<<8192, 256, 0, stream>>>(x, w1, b1, w2, b2, h, hh, cc);
  knn_topk<64><<<dim3(64, 8), 256, 0, stream>>>(h, hh, idx1);
  knn_topk<3><<<dim3(64, 8), 256, 0, stream>>>(x, cc, idx2);
  dg_stage<<<32768, 256, 0, stream>>>(h, idx1, wdg1b, bdg1, wdg2b, bdg2, featb);
  sn_stage<<<32768, 256, 0, stream>>>(idx2, wsn1b, bsn1, featb);
  conv3_gemm<<<dim3(8, 256), 256, 0, stream>>>(w3b, featb, b3, (float*)d_out);
}

// Round 3
// 2262.694 us; speedup vs baseline: 4.0742x; 1.6326x over previous
//
#include <hip/hip_runtime.h>
#include <stdint.h>

// LPDNet forward on gfx950.
// Layout decisions:
//   h     : (B,N,64) fp32 rows  -> coalesced gather + fp32-exact knn distances
//   featb : (B,N,512) bf16 rows -> [x1 | x2 | x3], rows feed conv3 GEMM and x2 gather
//   idx1/idx2 : (B,N,20) int32
// bf16 everywhere in the conv path (fp32 accum); tolerance is 2% of max|ref|.

#define NB 8
#define NP 4096
#define NPTS (NB*NP)

typedef float  floatx4 __attribute__((ext_vector_type(4)));
typedef short  short8  __attribute__((ext_vector_type(8)));

__device__ __forceinline__ unsigned short f2bf(float f) {
  union { float f; uint32_t u; } v; v.f = f;
  uint32_t r = v.u + 0x7fffu + ((v.u >> 16) & 1u);   // RNE
  return (unsigned short)(r >> 16);
}
__device__ __forceinline__ float bf2f(unsigned short h) {
  union { uint32_t u; float f; } v; v.u = ((uint32_t)h) << 16;
  return v.f;
}

__device__ __forceinline__ floatx4 mfma_bf16(short8 a, short8 b, floatx4 c) {
  return __builtin_amdgcn_mfma_f32_16x16x32_bf16(a, b, c, 0, 0, 0);
}

// ---------------- K0: fp32 -> bf16 weight conversion (runs every launch) ----
__global__ void cvt_weights(const float* a, int na, unsigned short* ab,
                            const float* b, int nb, unsigned short* bb,
                            const float* c, int nc, unsigned short* cb,
                            const float* d, int nd, unsigned short* db) {
  int i = blockIdx.x * 256 + threadIdx.x;
  if (i < na) ab[i] = f2bf(a[i]);
  if (i < nb) bb[i] = f2bf(b[i]);
  if (i < nc) cb[i] = f2bf(c[i]);
  if (i < nd) db[i] = f2bf(d[i]);
}

// ---------------- K1: conv1(3->64)+relu, conv2(64->64)+relu, plus xx sums ---
__global__ __launch_bounds__(256) void conv12(
    const float* __restrict__ xin, const float* __restrict__ w1,
    const float* __restrict__ b1, const float* __restrict__ w2,
    const float* __restrict__ b2, float* __restrict__ h,
    float* __restrict__ hh, float* __restrict__ cc) {
  int wave = threadIdx.x >> 6, lane = threadIdx.x & 63;
  int p = blockIdx.x * 4 + wave;                    // grid 8192
  __shared__ float s_h1[4][64];
  const float* xp = xin + p * 3;
  float c0 = xp[0], c1 = xp[1], c2 = xp[2];
  float v = b1[lane] + w1[lane*3+0]*c0 + w1[lane*3+1]*c1 + w1[lane*3+2]*c2;
  s_h1[wave][lane] = fmaxf(v, 0.f);
  __syncthreads();
  float acc = b2[lane];
  const float* wr = w2 + lane * 64;
  #pragma unroll
  for (int c = 0; c < 64; c += 4) {
    floatx4 w4 = *(const floatx4*)(wr + c);
    acc += w4[0]*s_h1[wave][c]   + w4[1]*s_h1[wave][c+1]
         + w4[2]*s_h1[wave][c+2] + w4[3]*s_h1[wave][c+3];
  }
  acc = fmaxf(acc, 0.f);
  h[p*64 + lane] = acc;
  float sq = acc * acc;
  #pragma unroll
  for (int off = 32; off; off >>= 1) sq += __shfl_xor(sq, off, 64);
  if (lane == 0) { hh[p] = sq; cc[p] = c0*c0 + c1*c1 + c2*c2; }
}

// ---------------- K2: fused pairwise distance + parallel top-20 --------------
// 64 rows/block, m-tiles of 64. Compute: 256 threads = 4x16 grid of 4x4 fp32
// register tiles. Selection: 4 threads per row, register top-20 lists, gated by
// a SHARED per-row threshold tau[row] = max over the row's lanes of their list
// minima (provably <= row running 20th-largest -> pruning is safe; LDS rmw
// races only loosen tau). Cuts insert-union probability ~0.9 -> ~0.1.
// Eviction by value only (exact fp32 ties among distinct points: measure-zero;
// only the neighbor SET matters downstream -- max over k).
template<int C>
__global__ __launch_bounds__(256) void knn_topk(
    const float* __restrict__ X, const float* __restrict__ XX,
    int* __restrict__ idx_out) {
  __shared__ float rowsT[C][68];
  __shared__ float mT[C][68];
  __shared__ float dots[64][68];   // pad 68: float4-aligned rows
  __shared__ float xxR[64];
  __shared__ float xxM[64];
  __shared__ float tau[64];
  int b = blockIdx.y;
  int r0 = blockIdx.x * 64;
  int t = threadIdx.x;
  const float* Xb = X + (size_t)b * NP * C;
  for (int e = t; e < C * 64; e += 256) {
    int r = e / C, c = e - r * C;
    rowsT[c][r] = Xb[(r0 + r) * C + c];
  }
  if (t < 64) { xxR[t] = XX[b * NP + r0 + t]; tau[t] = -__builtin_inff(); }

  float lv[20]; int li[20];
  #pragma unroll
  for (int s = 0; s < 20; s++) { lv[s] = -__builtin_inff(); li[s] = 0x7fffffff; }
  float minval = -__builtin_inff(); int minpos = 0;

  int tm = t & 15, tr = t >> 4;         // compute mapping
  int row = t >> 2, sub = t & 3;        // selection mapping

  for (int mt = 0; mt < NP / 64; mt++) {
    int m0 = mt * 64;
    for (int e = t; e < C * 64; e += 256) {
      int r = e / C, c = e - r * C;
      mT[c][r] = Xb[(m0 + r) * C + c];
    }
    if (t < 64) xxM[t] = XX[b * NP + m0 + t];
    __syncthreads();                       // staging done; prior select done
    float acc[4][4];
    #pragma unroll
    for (int i = 0; i < 4; i++)
      #pragma unroll
      for (int j = 0; j < 4; j++) acc[i][j] = 0.f;
    for (int c = 0; c < C; c++) {
      floatx4 av = *(floatx4*)&rowsT[c][tr * 4];
      floatx4 bv = *(floatx4*)&mT[c][tm * 4];
      #pragma unroll
      for (int i = 0; i < 4; i++)
        #pragma unroll
        for (int j = 0; j < 4; j++) acc[i][j] += av[i] * bv[j];
    }
    #pragma unroll
    for (int i = 0; i < 4; i++) {
      floatx4 sv;
      #pragma unroll
      for (int j = 0; j < 4; j++)
        sv[j] = 2.f * acc[i][j] - xxR[tr*4 + i] - xxM[tm*4 + j];
      *(floatx4*)&dots[tr*4 + i][tm*4] = sv;
    }
    __syncthreads();                       // dots ready
    // selection: 16 columns for (row, sub), gated by max(own min, shared tau)
    float gate = fmaxf(minval, tau[row]);
    floatx4 dv[4];
    #pragma unroll
    for (int q = 0; q < 4; q++) dv[q] = *(floatx4*)&dots[row][sub * 16 + q * 4];
    #pragma unroll
    for (int q = 0; q < 4; q++)
      #pragma unroll
      for (int j = 0; j < 4; j++) {
        float v = dv[q][j];
        if (v > gate) {
          int gi = m0 + sub * 16 + q * 4 + j;
          #pragma unroll
          for (int s = 0; s < 20; s++)
            if (s == minpos) { lv[s] = v; li[s] = gi; }
          minval = __builtin_inff();
          #pragma unroll
          for (int s = 0; s < 20; s++)
            if (lv[s] < minval) { minval = lv[s]; minpos = s; }
          gate = fmaxf(gate, minval);
        }
      }
    // publish my list-min as a row lower bound (races only loosen tau: safe)
    tau[row] = fmaxf(tau[row], minval);
  }
  // merge 4 per-thread lists -> row top-20 set (tie-break lower index)
  int base = (b * NP + r0 + row) * 20;
  for (int sel = 0; sel < 20; sel++) {
    float mybv = -__builtin_inff(); int mybi = 0x7fffffff, mybs = 0;
    #pragma unroll
    for (int s = 0; s < 20; s++) {
      bool better = lv[s] > mybv || (lv[s] == mybv && li[s] < mybi);
      if (better) { mybv = lv[s]; mybi = li[s]; mybs = s; }
    }
    float bv = mybv; int bi = mybi;
    float ov = __shfl_xor(bv, 1, 64); int oi = __shfl_xor(bi, 1, 64);
    if (ov > bv || (ov == bv && oi < bi)) { bv = ov; bi = oi; }
    ov = __shfl_xor(bv, 2, 64); oi = __shfl_xor(bi, 2, 64);
    if (ov > bv || (ov == bv && oi < bi)) { bv = ov; bi = oi; }
    if (sub == 0) idx_out[base + sel] = bi;
    if (bi == mybi) {                      // column sets disjoint -> unique owner
      #pragma unroll
      for (int s = 0; s < 20; s++)
        if (s == mybs) { lv[s] = -__builtin_inff(); li[s] = 0x7fffffff; }
    }
  }
}

// ---------------- K3: graph_feature(h,idx1) -> dg1 -> max -> dg2 -> max ------
__global__ __launch_bounds__(256) void dg_stage(
    const float* __restrict__ h, const int* __restrict__ idx1,
    const unsigned short* __restrict__ w1b, const float* __restrict__ bia1,
    const unsigned short* __restrict__ w2b, const float* __restrict__ bia2,
    unsigned short* __restrict__ featb) {
  __shared__ unsigned short s_a[32][136];
  __shared__ unsigned short s_v[32][136];
  __shared__ int s_nb[20];
  int p = blockIdx.x;
  int b = p >> 12, n = p & 4095;
  int t = threadIdx.x;
  int lane = t & 63, wave = t >> 6;
  if (t < 20) s_nb[t] = idx1[p * 20 + t];
  __syncthreads();
  const float* hb = h + (size_t)b * NP * 64;
  const float* hc = hb + n * 64;
  for (int e = t; e < 2560; e += 256) {
    int k = e >> 7, c = e & 127;
    float v = (c < 64) ? (hb[s_nb[k] * 64 + c] - hc[c]) : hc[c - 64];
    s_a[k][c] = f2bf(v);
  }
  for (int e = t; e < 1536; e += 256) s_a[20 + (e >> 7)][e & 127] = 0;
  __syncthreads();
  int quad = lane >> 4, mrow = lane & 15;
  int nblock = wave * 32;
  floatx4 acc[2][2];
  #pragma unroll
  for (int i = 0; i < 2; i++)
    #pragma unroll
    for (int j = 0; j < 2; j++) acc[i][j] = (floatx4)0.f;
  #pragma unroll
  for (int ks = 0; ks < 4; ks++) {
    int k0 = ks * 32 + quad * 8;
    short8 a0 = *(short8*)&s_a[mrow][k0];
    short8 a1 = *(short8*)&s_a[16 + mrow][k0];
    short8 w0 = *(const short8*)(w1b + (nblock + mrow) * 128 + k0);
    short8 w1v = *(const short8*)(w1b + (nblock + 16 + mrow) * 128 + k0);
    acc[0][0] = mfma_bf16(a0, w0, acc[0][0]);
    acc[1][0] = mfma_bf16(a1, w0, acc[1][0]);
    acc[0][1] = mfma_bf16(a0, w1v, acc[0][1]);
    acc[1][1] = mfma_bf16(a1, w1v, acc[1][1]);
  }
  #pragma unroll
  for (int mt = 0; mt < 2; mt++)
    #pragma unroll
    for (int ns = 0; ns < 2; ns++)
      #pragma unroll
      for (int r = 0; r < 4; r++) {
        int m = mt * 16 + quad * 4 + r;
        int o = nblock + ns * 16 + mrow;
        s_v[m][o] = f2bf(fmaxf(acc[mt][ns][r] + bia1[o], 0.f));
      }
  __syncthreads();
  if (t < 128) {
    float mx = 0.f;
    for (int k = 0; k < 20; k++) mx = fmaxf(mx, bf2f(s_v[k][t]));
    featb[p * 512 + t] = f2bf(mx);
  }
  #pragma unroll
  for (int i = 0; i < 2; i++)
    #pragma unroll
    for (int j = 0; j < 2; j++) acc[i][j] = (floatx4)0.f;
  #pragma unroll
  for (int ks = 0; ks < 4; ks++) {
    int k0 = ks * 32 + quad * 8;
    short8 a0 = *(short8*)&s_v[mrow][k0];
    short8 a1 = *(short8*)&s_v[16 + mrow][k0];
    short8 w0 = *(const short8*)(w2b + (nblock + mrow) * 128 + k0);
    short8 w1v = *(const short8*)(w2b + (nblock + 16 + mrow) * 128 + k0);
    acc[0][0] = mfma_bf16(a0, w0, acc[0][0]);
    acc[1][0] = mfma_bf16(a1, w0, acc[1][0]);
    acc[0][1] = mfma_bf16(a0, w1v, acc[0][1]);
    acc[1][1] = mfma_bf16(a1, w1v, acc[1][1]);
  }
  float vmax[2] = {0.f, 0.f};
  #pragma unroll
  for (int mt = 0; mt < 2; mt++)
    #pragma unroll
    for (int ns = 0; ns < 2; ns++)
      #pragma unroll
      for (int r = 0; r < 4; r++) {
        int m = mt * 16 + quad * 4 + r;
        if (m < 20) {
          int o = nblock + ns * 16 + mrow;
          vmax[ns] = fmaxf(vmax[ns], fmaxf(acc[mt][ns][r] + bia2[o], 0.f));
        }
      }
  #pragma unroll
  for (int ns = 0; ns < 2; ns++) {
    float v = vmax[ns];
    v = fmaxf(v, __shfl_xor(v, 16, 64));
    v = fmaxf(v, __shfl_xor(v, 32, 64));
    if (lane < 16) featb[p * 512 + 128 + nblock + ns * 16 + lane] = f2bf(v);
  }
}

// ---------------- K4: graph_feature(x2,idx2) -> sn1 -> max -------------------
__global__ __launch_bounds__(256) void sn_stage(
    const int* __restrict__ idx2, const unsigned short* __restrict__ wb,
    const float* __restrict__ bias, unsigned short* __restrict__ featb) {
  __shared__ unsigned short s_a[32][264];
  __shared__ int s_nb[20];
  int p = blockIdx.x;
  int b = p >> 12;
  int t = threadIdx.x;
  int lane = t & 63, wave = t >> 6;
  if (t < 20) s_nb[t] = idx2[p * 20 + t];
  __syncthreads();
  const unsigned short* x2b = featb + (size_t)b * NP * 512 + 128;
  const unsigned short* x2c = featb + (size_t)p * 512 + 128;
  for (int e = t; e < 5120; e += 256) {
    int k = e >> 8, c = e & 255;
    float v = (c < 128) ? (bf2f(x2b[(size_t)s_nb[k] * 512 + c]) - bf2f(x2c[c]))
                        : bf2f(x2c[c - 128]);
    s_a[k][c] = f2bf(v);
  }
  for (int e = t; e < 3072; e += 256) s_a[20 + (e >> 8)][e & 255] = 0;
  __syncthreads();
  int quad = lane >> 4, mrow = lane & 15;
  int nblock = wave * 64;
  floatx4 acc[2][4];
  #pragma unroll
  for (int i = 0; i < 2; i++)
    #pragma unroll
    for (int j = 0; j < 4; j++) acc[i][j] = (floatx4)0.f;
  #pragma unroll
  for (int ks = 0; ks < 8; ks++) {
    int k0 = ks * 32 + quad * 8;
    short8 a0 = *(short8*)&s_a[mrow][k0];
    short8 a1 = *(short8*)&s_a[16 + mrow][k0];
    #pragma unroll
    for (int ns = 0; ns < 4; ns++) {
      short8 w = *(const short8*)(wb + (nblock + ns * 16 + mrow) * 256 + k0);
      acc[0][ns] = mfma_bf16(a0, w, acc[0][ns]);
      acc[1][ns] = mfma_bf16(a1, w, acc[1][ns]);
    }
  }
  float vmax[4] = {0.f, 0.f, 0.f, 0.f};
  #pragma unroll
  for (int mt = 0; mt < 2; mt++)
    #pragma unroll
    for (int ns = 0; ns < 4; ns++)
      #pragma unroll
      for (int r = 0; r < 4; r++) {
        int m = mt * 16 + quad * 4 + r;
        if (m < 20) {
          int o = nblock + ns * 16 + mrow;
          vmax[ns] = fmaxf(vmax[ns], fmaxf(acc[mt][ns][r] + bias[o], 0.f));
        }
      }
  #pragma unroll
  for (int ns = 0; ns < 4; ns++) {
    float v = vmax[ns];
    v = fmaxf(v, __shfl_xor(v, 16, 64));
    v = fmaxf(v, __shfl_xor(v, 32, 64));
    if (lane < 16) featb[p * 512 + 256 + nblock + ns * 16 + lane] = f2bf(v);
  }
}

// ---------------- K5: conv3 GEMM ---------------------------------------------
__global__ __launch_bounds__(256) void conv3_gemm(
    const unsigned short* __restrict__ w3b, const unsigned short* __restrict__ featb,
    const float* __restrict__ b3, float* __restrict__ out) {
  __shared__ unsigned short s_a[128][40];
  __shared__ unsigned short s_b[128][40];
  int o0 = blockIdx.x * 128, p0 = blockIdx.y * 128;
  int t = threadIdx.x, lane = t & 63, wave = t >> 6;
  int wy = wave >> 1, wx = wave & 1;
  int quad = lane >> 4, l15 = lane & 15;
  floatx4 acc[4][4];
  #pragma unroll
  for (int i = 0; i < 4; i++)
    #pragma unroll
    for (int j = 0; j < 4; j++) acc[i][j] = (floatx4)0.f;
  for (int kc = 0; kc < 16; kc++) {
    __syncthreads();
    for (int e = t; e < 512; e += 256) {
      int r = e >> 2, c8 = (e & 3) * 8;
      *(short8*)&s_a[r][c8] = *(const short8*)(w3b + (size_t)(o0 + r) * 512 + kc * 32 + c8);
    }
    for (int e = t; e < 512; e += 256) {
      int r = e >> 2, c8 = (e & 3) * 8;
      *(short8*)&s_b[r][c8] = *(const short8*)(featb + (size_t)(p0 + r) * 512 + kc * 32 + c8);
    }
    __syncthreads();
    int k0 = quad * 8;
    short8 af[4], bfr[4];
    #pragma unroll
    for (int i = 0; i < 4; i++) af[i] = *(short8*)&s_a[wy * 64 + i * 16 + l15][k0];
    #pragma unroll
    for (int j = 0; j < 4; j++) bfr[j] = *(short8*)&s_b[wx * 64 + j * 16 + l15][k0];
    #pragma unroll
    for (int i = 0; i < 4; i++)
      #pragma unroll
      for (int j = 0; j < 4; j++) acc[i][j] = mfma_bf16(af[i], bfr[j], acc[i][j]);
  }
  #pragma unroll
  for (int i = 0; i < 4; i++)
    #pragma unroll
    for (int j = 0; j < 4; j++) {
      int pl = p0 + wx * 64 + j * 16 + l15;
      int bI = pl >> 12, n = pl & 4095;
      #pragma unroll
      for (int r = 0; r < 4; r++) {
        int o = o0 + wy * 64 + i * 16 + quad * 4 + r;
        out[(size_t)(bI * 1024 + o) * 4096 + n] = fmaxf(acc[i][j][r] + b3[o], 0.f);
      }
    }
}

// ---------------- launcher ---------------------------------------------------
extern "C" void kernel_launch(void* const* d_in, const int* in_sizes, int n_in,
                              void* d_out, int out_size, void* d_ws, size_t ws_size,
                              hipStream_t stream) {
  const float* x    = (const float*)d_in[0];
  const float* w1   = (const float*)d_in[1];
  const float* b1   = (const float*)d_in[2];
  const float* w2   = (const float*)d_in[3];
  const float* b2   = (const float*)d_in[4];
  const float* wdg1 = (const float*)d_in[5];
  const float* bdg1 = (const float*)d_in[6];
  const float* wdg2 = (const float*)d_in[7];
  const float* bdg2 = (const float*)d_in[8];
  const float* wsn1 = (const float*)d_in[9];
  const float* bsn1 = (const float*)d_in[10];
  const float* w3   = (const float*)d_in[11];
  const float* b3   = (const float*)d_in[12];

  float* ws = (float*)d_ws;
  float* h  = ws;                           // 2,097,152
  float* hh = ws + 2097152;                 //    32,768
  float* cc = ws + 2129920;                 //    32,768
  int* idx1 = (int*)(ws + 2162688);         //   655,360
  int* idx2 = (int*)(ws + 2818048);         //   655,360
  unsigned short* featb = (unsigned short*)(ws + 3473408);   // 16,777,216 bf16
  unsigned short* wdg1b = (unsigned short*)(ws + 11862016);
  unsigned short* wdg2b = (unsigned short*)(ws + 11870208);
  unsigned short* wsn1b = (unsigned short*)(ws + 11878400);
  unsigned short* w3b   = (unsigned short*)(ws + 11911168);

  cvt_weights<<<2048, 256, 0, stream>>>(wdg1, 16384, wdg1b, wdg2, 16384, wdg2b,
                                        wsn1, 65536, wsn1b, w3, 524288, w3b);
  conv12<<<8192, 256, 0, stream>>>(x, w1, b1, w2, b2, h, hh, cc);
  knn_topk<64><<<dim3(64, 8), 256, 0, stream>>>(h, hh, idx1);
  knn_topk<3><<<dim3(64, 8), 256, 0, stream>>>(x, cc, idx2);
  dg_stage<<<32768, 256, 0, stream>>>(h, idx1, wdg1b, bdg1, wdg2b, bdg2, featb);
  sn_stage<<<32768, 256, 0, stream>>>(idx2, wsn1b, bsn1, featb);
  conv3_gemm<<<dim3(8, 256), 256, 0, stream>>>(w3b, featb, b3, (float*)d_out);
}